// Round 13
// baseline (245.178 us; speedup 1.0000x reference)
//
#include <hip/hip_runtime.h>
#include <hip/hip_cooperative_groups.h>
#include <math.h>

namespace cg = cooperative_groups;

// (b,n,h,d) = (4,8192,8,64), fp32.
// Groups: i=0: g=3,r=1,off=0,hmin=0,seg=2048  -> 8192 covered pos/b
//         i=1: g=3,r=2,off=1,hmin=3,seg=4096  -> 4096 covered pos/b (pos%2==1)
//         i=2: g=2,r=4,off=2,hmin=6,seg=8192  -> 2048 covered pos/b (pos%4==2)
//
// R13: single cooperative kernel, compact-bf16 x staging.
// R1-R12 falsified every structural theory (MLP/occupancy/coupling/DMA/
// persistence/segment-shape/byte-set/chain/L1-bypass); gather-compute kernels
// are pinned at ~2 TB/s reads while pure streams hit 6.9-19 TB/s. Remaining
// levers: total bytes (312->235 MB: x staged as compact contiguous bf16
// 21 MB instead of scattered fp32 47 MB) and fixed overhead (4 launches -> 1
// cooperative kernel with 2 grid syncs).

#define NB 4
#define NN 8192
#define NH 8
#define ND 64
#define NPART_STRIDE 192
#define NBLOCKS 448
#define NWAVES  (NBLOCKS * 4)          // 1792

// compact-x element bases (bf16 elements)
#define XBASE_G1 (32768u * 192u)               // after g0: 4b*8192 inst * 192
#define XBASE_G2 (XBASE_G1 + 16384u * 192u)    // after g1: 4b*4096 inst * 192
#define XTOTAL   (XBASE_G2 + 8192u * 128u)     // + g2: 4b*2048 inst * 128

__device__ __forceinline__ unsigned short f2b(float f) {   // rne bf16
    unsigned int u = __float_as_uint(f);
    u = (u + 0x7FFFu + ((u >> 16) & 1u)) >> 16;
    return (unsigned short)u;
}
__device__ __forceinline__ float b2f(unsigned short s) {
    return __uint_as_float(((unsigned int)s) << 16);
}

template<int G>
__device__ __forceinline__ void phase1(
    const float* __restrict__ Q, const float* __restrict__ K,
    const float* __restrict__ V, unsigned short* __restrict__ xc,
    float* __restrict__ partials,
    int b, int wl, int wid, int r, int off, int seglen,
    int hmin, size_t xbase, int ninst, int xrec)
{
    const int lane = threadIdx.x & 63;
    const int sg   = lane >> 4;     // 16-lane sub-group = one position
    const int l    = lane & 15;     // lane owns d in [4l, 4l+4)

    float xs[G][4];
    #pragma unroll
    for (int q = 0; q < G; ++q)
        #pragma unroll
        for (int e = 0; e < 4; ++e) xs[q][e] = 0.f;

    for (int t = 0; t < 8; ++t) {
        const int j   = wl * 32 + t * 4 + sg;
        const int pos = (j >> 11) * seglen + off + (j & 2047) * r;
        const size_t rb = (((size_t)b * NN + pos) * NH + hmin) * ND + 4 * l;

        float4 qv[G], kv[G], vv[G];
        #pragma unroll
        for (int q = 0; q < G; ++q) {
            qv[q] = *(const float4*)(Q + rb + q * ND);
            kv[q] = *(const float4*)(K + rb + q * ND);
            vv[q] = *(const float4*)(V + rb + q * ND);
        }

        float sc[G][G];
        #pragma unroll
        for (int q = 0; q < G; ++q)
            #pragma unroll
            for (int k = 0; k < G; ++k)
                sc[q][k] = qv[q].x * kv[k].x + qv[q].y * kv[k].y
                         + qv[q].z * kv[k].z + qv[q].w * kv[k].w;

        #pragma unroll
        for (int o = 8; o >= 1; o >>= 1)
            #pragma unroll
            for (int q = 0; q < G; ++q)
                #pragma unroll
                for (int k = 0; k < G; ++k)
                    sc[q][k] += __shfl_xor(sc[q][k], o);

        #pragma unroll
        for (int q = 0; q < G; ++q) {
            float m = -INFINITY;
            #pragma unroll
            for (int k = 0; k < G; ++k) { sc[q][k] *= 0.125f; m = fmaxf(m, sc[q][k]); }
            float ssum = 0.f;
            #pragma unroll
            for (int k = 0; k < G; ++k) { sc[q][k] = __expf(sc[q][k] - m); ssum += sc[q][k]; }
            const float rs = 1.f / ssum;
            #pragma unroll
            for (int k = 0; k < G; ++k) sc[q][k] *= rs;
        }

        // compact bf16 record for this covered instance: [q][64] elems
        const size_t xo0 = xbase + ((size_t)b * ninst + j) * xrec;
        #pragma unroll
        for (int q = 0; q < G; ++q) {
            float xe0 = 0.f, xe1 = 0.f, xe2 = 0.f, xe3 = 0.f;
            #pragma unroll
            for (int k = 0; k < G; ++k) {
                const float aw = sc[q][k];
                xe0 += aw * vv[k].x; xe1 += aw * vv[k].y;
                xe2 += aw * vv[k].z; xe3 += aw * vv[k].w;
            }
            ushort4 u;
            u.x = f2b(xe0); u.y = f2b(xe1); u.z = f2b(xe2); u.w = f2b(xe3);
            *(ushort4*)(xc + xo0 + q * 64 + 4 * l) = u;
            xs[q][0] += xe0; xs[q][1] += xe1; xs[q][2] += xe2; xs[q][3] += xe3;
        }
    }

    // wave-level reduce across the 4 sub-groups (register-only)
    #pragma unroll
    for (int q = 0; q < G; ++q)
        #pragma unroll
        for (int e = 0; e < 4; ++e) {
            xs[q][e] += __shfl_xor(xs[q][e], 16);
            xs[q][e] += __shfl_xor(xs[q][e], 32);
        }

    if (lane < 16) {
        #pragma unroll
        for (int q = 0; q < G; ++q)
            *(float4*)(partials + (size_t)wid * NPART_STRIDE + q * 64 + 4 * l) =
                make_float4(xs[q][0], xs[q][1], xs[q][2], xs[q][3]);
    }
}

__global__ __launch_bounds__(256)
void sda_fused(const float* __restrict__ Q, const float* __restrict__ K,
               const float* __restrict__ V, float* __restrict__ out,
               unsigned short* __restrict__ xc, float* __restrict__ partials,
               float* __restrict__ inv)
{
    cg::grid_group grid = cg::this_grid();
    const int bid = blockIdx.x;
    const int tid = threadIdx.x;
    const int w   = tid >> 6;
    const int wid = bid * 4 + w;

    // ---------------- phase 1: attention + compact-x + wave partials --------
    if (bid < 256) {                         // g0: 64 blocks per b
        const int b = bid >> 6, wl = (bid & 63) * 4 + w;
        phase1<3>(Q, K, V, xc, partials, b, wl, wid, 1, 0, 2048, 0,
                  0, 8192, 192);
    } else if (bid < 384) {                  // g1: 32 blocks per b
        const int loc = bid - 256;
        const int b = loc >> 5, wl = (loc & 31) * 4 + w;
        phase1<3>(Q, K, V, xc, partials, b, wl, wid, 2, 1, 4096, 3,
                  XBASE_G1, 4096, 192);
    } else {                                 // g2: 16 blocks per b
        const int loc = bid - 384;
        const int b = loc >> 4, wl = (loc & 15) * 4 + w;
        phase1<2>(Q, K, V, xc, partials, b, wl, wid, 4, 2, 8192, 6,
                  XBASE_G2, 2048, 128);
    }

    __threadfence();
    grid.sync();

    // ---------------- phase 2: reduce partials -> inv (blocks 0..31) --------
    if (bid < 32) {
        const int b = bid >> 3, h = bid & 7;
        const int d = tid & 63, part = tid >> 6;
        int qi, wstart, cnt;
        if (h < 3)      { qi = h;     wstart = b * 256;        cnt = 256; }
        else if (h < 6) { qi = h - 3; wstart = 1024 + b * 128; cnt = 128; }
        else            { qi = h - 6; wstart = 1536 + b * 64;  cnt = 64;  }
        float s = 0.f;
        #pragma unroll 4
        for (int c = part; c < cnt; c += 4)
            s += partials[(size_t)(wstart + c) * NPART_STRIDE + qi * 64 + d];
        __shared__ float sred[4][64];
        sred[part][d] = s;
        __syncthreads();
        if (part == 0) {
            const float tot = sred[0][d] + sred[1][d] + sred[2][d] + sred[3][d];
            inv[bid * 64 + d] = 1.f / (3.f * (tot + 1e-8f));
        }
    }

    __threadfence();
    grid.sync();

    // ---------------- phase 3: scale compact x into out (all blocks) --------
    const int total4 = NB * NN * NH * ND / 4;          // 4,194,304 float4
    const int stride = NBLOCKS * 256;
    for (int idx = bid * 256 + tid; idx < total4; idx += stride) {
        const int d4  = idx & 15;
        const int rem = idx >> 4;
        const int h   = rem & 7;
        const int pos = (rem >> 3) & 8191;
        const int b   = rem >> 16;

        float4 o = make_float4(0.f, 0.f, 0.f, 0.f);
        size_t xo = (size_t)-1;
        if (h < 3) {
            xo = ((size_t)b * 8192 + pos) * 192 + h * 64 + 4 * d4;
        } else if (h < 6) {
            if (pos & 1) {
                const int j = (pos >> 12) * 2048 + ((pos & 4095) >> 1);
                xo = XBASE_G1 + ((size_t)b * 4096 + j) * 192 + (h - 3) * 64 + 4 * d4;
            }
        } else {
            if ((pos & 3) == 2) {
                const int j = (pos - 2) >> 2;
                xo = XBASE_G2 + ((size_t)b * 2048 + j) * 128 + (h - 6) * 64 + 4 * d4;
            }
        }
        if (xo != (size_t)-1) {
            const ushort4 u = *(const ushort4*)(xc + xo);
            const float4 f = ((const float4*)inv)[(b * 8 + h) * 16 + d4];
            o = make_float4(b2f(u.x) * f.x, b2f(u.y) * f.y,
                            b2f(u.z) * f.z, b2f(u.w) * f.w);
        }
        ((float4*)out)[idx] = o;
    }
}

extern "C" void kernel_launch(void* const* d_in, const int* in_sizes, int n_in,
                              void* d_out, int out_size, void* d_ws, size_t ws_size,
                              hipStream_t stream)
{
    const float* Q = (const float*)d_in[0];
    const float* K = (const float*)d_in[1];
    const float* V = (const float*)d_in[2];
    float* out = (float*)d_out;

    unsigned short* xc = (unsigned short*)d_ws;                // 21 MB bf16
    float* partials = (float*)((char*)d_ws + 22u * 1024u * 1024u); // 1.4 MB
    float* inv      = partials + (size_t)NWAVES * NPART_STRIDE;    // 8 KB

    void* args[] = { (void*)&Q, (void*)&K, (void*)&V, (void*)&out,
                     (void*)&xc, (void*)&partials, (void*)&inv };
    hipLaunchCooperativeKernel((const void*)sda_fused, dim3(NBLOCKS), dim3(256),
                               args, 0, stream);
}

// Round 14
// 48.821 us; speedup vs baseline: 5.0220x; 5.0220x over previous
//
#include <hip/hip_runtime.h>
#include <math.h>

// (b,n,h,d) = (4,8192,8,64), fp32.
// Groups: i=0: g=3,r=1,off=0,hmin=0,seg=2048  -> 8192 covered pos/b
//         i=1: g=3,r=2,off=1,hmin=3,seg=4096  -> 4096 covered pos/b (pos%2==1)
//         i=2: g=2,r=4,off=2,hmin=6,seg=8192  -> 2048 covered pos/b (pos%4==2)
//
// R14: compact-bf16 x staging (R13's content) on the proven 4-kernel vehicle
// (R13's coop-launch vehicle was the disaster: 245us). 13 structural theories
// falsified; pass1-type kernels pinned at ~4 TB/s CU-side -> remaining lever
// is BYTES: pass1 writes 21MB compact bf16 (was 47MB scattered fp32);
// pass3 reads 21MB (was 42MB). Sums stay fp32 (R13 validated: absmax 0.0625).

#define NB 4
#define NN 8192
#define NH 8
#define ND 64
#define NPART_STRIDE 192       // per-WAVE partial: g*64 floats (max g=3)
#define N_BLOCKS_P1 1792       // 4b*(256+128+64) chunks of 32 positions
#define N_WAVES_P1  (N_BLOCKS_P1 * 4)

// compact-x element offsets (bf16 elements)
#define XBASE_G1 (32768u * 192u)               // after g0: 4b*8192 inst * 192
#define XBASE_G2 (XBASE_G1 + 16384u * 192u)    // after g1: 4b*4096 inst * 192

__device__ __forceinline__ unsigned short f2b(float f) {   // rne bf16
    unsigned int u = __float_as_uint(f);
    u = (u + 0x7FFFu + ((u >> 16) & 1u)) >> 16;
    return (unsigned short)u;
}
__device__ __forceinline__ float b2f(unsigned short s) {
    return __uint_as_float(((unsigned int)s) << 16);
}

template<int G, int IT>
__device__ __forceinline__ void pass1_work(
    const float* __restrict__ Q, const float* __restrict__ K,
    const float* __restrict__ V, unsigned short* __restrict__ xc,
    float* __restrict__ partials,
    int b, int chunk, int r, int off, int hmin, int seglen,
    size_t xbase, int ninst, int xrec)
{
    const int tid  = threadIdx.x;   // 256 threads = 4 waves, independent
    const int w    = tid >> 6;
    const int lane = tid & 63;
    const int sg   = lane >> 4;     // 16-lane sub-group = one position
    const int l    = lane & 15;     // lane owns d in [4l, 4l+4)

    size_t rowbase[IT];
    int jj[IT];
    #pragma unroll
    for (int it = 0; it < IT; ++it) {
        const int j   = chunk * (16 * IT) + w * (4 * IT) + it * 4 + sg;
        const int pos = (j >> 11) * seglen + off + (j & 2047) * r;
        jj[it] = j;
        rowbase[it] = (((size_t)b * NN + pos) * NH + hmin) * ND + 4 * l;
    }

    float4 qv[IT][G], kv[IT][G], vv[IT][G];
    #pragma unroll
    for (int it = 0; it < IT; ++it)
        #pragma unroll
        for (int q = 0; q < G; ++q) {
            qv[it][q] = *(const float4*)(Q + rowbase[it] + q * ND);
            kv[it][q] = *(const float4*)(K + rowbase[it] + q * ND);
            vv[it][q] = *(const float4*)(V + rowbase[it] + q * ND);
        }

    float xs[G][4];
    #pragma unroll
    for (int q = 0; q < G; ++q)
        #pragma unroll
        for (int e = 0; e < 4; ++e) xs[q][e] = 0.f;

    #pragma unroll
    for (int it = 0; it < IT; ++it) {
        float sc[G][G];
        #pragma unroll
        for (int q = 0; q < G; ++q)
            #pragma unroll
            for (int k = 0; k < G; ++k)
                sc[q][k] = qv[it][q].x * kv[it][k].x + qv[it][q].y * kv[it][k].y
                         + qv[it][q].z * kv[it][k].z + qv[it][q].w * kv[it][k].w;

        // butterfly reduce across the 16 lanes of this sub-group
        #pragma unroll
        for (int o = 8; o >= 1; o >>= 1)
            #pragma unroll
            for (int q = 0; q < G; ++q)
                #pragma unroll
                for (int k = 0; k < G; ++k)
                    sc[q][k] += __shfl_xor(sc[q][k], o);

        #pragma unroll
        for (int q = 0; q < G; ++q) {
            float m = -INFINITY;
            #pragma unroll
            for (int k = 0; k < G; ++k) { sc[q][k] *= 0.125f; m = fmaxf(m, sc[q][k]); }
            float ssum = 0.f;
            #pragma unroll
            for (int k = 0; k < G; ++k) { sc[q][k] = __expf(sc[q][k] - m); ssum += sc[q][k]; }
            const float rs = 1.f / ssum;
            #pragma unroll
            for (int k = 0; k < G; ++k) sc[q][k] *= rs;
        }

        // compact bf16 record: [instance][q][64] elems, contiguous
        const size_t xo0 = xbase + ((size_t)b * ninst + jj[it]) * xrec;
        #pragma unroll
        for (int q = 0; q < G; ++q) {
            float xe0 = 0.f, xe1 = 0.f, xe2 = 0.f, xe3 = 0.f;
            #pragma unroll
            for (int k = 0; k < G; ++k) {
                const float aw = sc[q][k];
                xe0 += aw * vv[it][k].x; xe1 += aw * vv[it][k].y;
                xe2 += aw * vv[it][k].z; xe3 += aw * vv[it][k].w;
            }
            ushort4 u;
            u.x = f2b(xe0); u.y = f2b(xe1); u.z = f2b(xe2); u.w = f2b(xe3);
            *(ushort4*)(xc + xo0 + q * 64 + 4 * l) = u;
            xs[q][0] += xe0; xs[q][1] += xe1; xs[q][2] += xe2; xs[q][3] += xe3;
        }
    }

    // wave-level reduction across the 4 sub-groups (register-only)
    #pragma unroll
    for (int q = 0; q < G; ++q)
        #pragma unroll
        for (int e = 0; e < 4; ++e) {
            xs[q][e] += __shfl_xor(xs[q][e], 16);
            xs[q][e] += __shfl_xor(xs[q][e], 32);
        }

    if (lane < 16) {
        const int wid = blockIdx.x * 4 + w;
        #pragma unroll
        for (int q = 0; q < G; ++q)
            *(float4*)(partials + (size_t)wid * NPART_STRIDE + q * 64 + 4 * l) =
                make_float4(xs[q][0], xs[q][1], xs[q][2], xs[q][3]);
    }
}

__global__ __launch_bounds__(256)
void sda_pass1(const float* __restrict__ Q, const float* __restrict__ K,
               const float* __restrict__ V, unsigned short* __restrict__ xc,
               float* __restrict__ partials)
{
    const int bid = blockIdx.x;
    if (bid < 1024) {                      // group 0: 4 b * 256 chunks
        const int b = bid >> 8, chunk = bid & 255;
        pass1_work<3, 2>(Q, K, V, xc, partials, b, chunk, 1, 0, 0, 2048,
                         0, 8192, 192);
    } else if (bid < 1536) {               // group 1: 4 b * 128 chunks
        const int loc = bid - 1024;
        const int b = loc >> 7, chunk = loc & 127;
        pass1_work<3, 2>(Q, K, V, xc, partials, b, chunk, 2, 1, 3, 4096,
                         XBASE_G1, 4096, 192);
    } else {                               // group 2: 4 b * 64 chunks
        const int loc = bid - 1536;
        const int b = loc >> 6, chunk = loc & 63;
        pass1_work<2, 2>(Q, K, V, xc, partials, b, chunk, 4, 2, 6, 8192,
                         XBASE_G2, 2048, 128);
    }
}

// pass2a: 256 blocks = (bh 0..31) x (slice 0..7); coalesced wave-partial reduce.
__global__ __launch_bounds__(256)
void sda_pass2a(const float* __restrict__ partials, float* __restrict__ partial2)
{
    const int bid   = blockIdx.x;
    const int bh    = bid >> 3;
    const int slice = bid & 7;
    const int b     = bh >> 3;
    const int h     = bh & 7;
    const int d     = threadIdx.x & 63;
    const int part  = threadIdx.x >> 6;   // 4-way split of the slice
    int qi, wstart, cnt;
    if (h < 3)      { qi = h;     wstart = b * 1024;       cnt = 1024; }
    else if (h < 6) { qi = h - 3; wstart = 4096 + b * 512; cnt = 512;  }
    else            { qi = h - 6; wstart = 6144 + b * 256; cnt = 256;  }
    const int len = cnt >> 3;             // 128 / 64 / 32
    const int c0  = wstart + slice * len;
    float s = 0.f;
    #pragma unroll 4
    for (int c = part; c < len; c += 4)
        s += partials[(size_t)(c0 + c) * NPART_STRIDE + qi * 64 + d];
    __shared__ float sred[4][64];
    sred[part][d] = s;
    __syncthreads();
    if (part == 0)
        partial2[(size_t)bid * 64 + d] = sred[0][d] + sred[1][d] + sred[2][d] + sred[3][d];
}

// pass2b: finish 8 slice-partials per (b,h,d) -> inv
__global__ __launch_bounds__(256)
void sda_pass2b(const float* __restrict__ partial2, float* __restrict__ inv)
{
    const int t = blockIdx.x * 256 + threadIdx.x;   // 2048 = bh*64 + d
    if (t >= NB * NH * ND) return;
    const int bh = t >> 6;
    const int d  = t & 63;
    float s = 0.f;
    #pragma unroll
    for (int sl = 0; sl < 8; ++sl)
        s += partial2[(size_t)(bh * 8 + sl) * 64 + d];
    inv[t] = 1.f / (3.f * (s + 1e-8f));
}

// pass3: read compact bf16 x, scale, write full out (zeros uncovered).
__global__ __launch_bounds__(256)
void sda_pass3(const unsigned short* __restrict__ xc, float* __restrict__ out,
               const float* __restrict__ inv)
{
    const int total4 = NB * NN * NH * ND / 4;   // 4,194,304 float4s
    for (int idx = blockIdx.x * 256 + threadIdx.x; idx < total4;
         idx += gridDim.x * 256) {
        const int d4  = idx & 15;
        const int rem = idx >> 4;
        const int h   = rem & 7;
        const int pos = (rem >> 3) & 8191;
        const int b   = rem >> 16;

        float4 o = make_float4(0.f, 0.f, 0.f, 0.f);
        size_t xo = (size_t)-1;
        if (h < 3) {
            xo = ((size_t)b * 8192 + pos) * 192 + h * 64 + 4 * d4;
        } else if (h < 6) {
            if (pos & 1) {
                const int j = (pos >> 12) * 2048 + ((pos & 4095) >> 1);
                xo = XBASE_G1 + ((size_t)b * 4096 + j) * 192 + (h - 3) * 64 + 4 * d4;
            }
        } else {
            if ((pos & 3) == 2) {
                const int j = (pos - 2) >> 2;
                xo = XBASE_G2 + ((size_t)b * 2048 + j) * 128 + (h - 6) * 64 + 4 * d4;
            }
        }
        if (xo != (size_t)-1) {
            const ushort4 u = *(const ushort4*)(xc + xo);
            const float4 f = ((const float4*)inv)[(b * 8 + h) * 16 + d4];
            o = make_float4(b2f(u.x) * f.x, b2f(u.y) * f.y,
                            b2f(u.z) * f.z, b2f(u.w) * f.w);
        }
        ((float4*)out)[idx] = o;
    }
}

extern "C" void kernel_launch(void* const* d_in, const int* in_sizes, int n_in,
                              void* d_out, int out_size, void* d_ws, size_t ws_size,
                              hipStream_t stream)
{
    const float* Q = (const float*)d_in[0];
    const float* K = (const float*)d_in[1];
    const float* V = (const float*)d_in[2];
    float* out = (float*)d_out;

    unsigned short* xc = (unsigned short*)d_ws;                    // ~21 MB bf16
    float* partials = (float*)((char*)d_ws + 22u * 1024u * 1024u); // 5.5 MB
    float* partial2 = partials + (size_t)N_WAVES_P1 * NPART_STRIDE;
    float* inv      = partial2 + 256 * 64;

    hipLaunchKernelGGL(sda_pass1,  dim3(N_BLOCKS_P1), dim3(256), 0, stream,
                       Q, K, V, xc, partials);
    hipLaunchKernelGGL(sda_pass2a, dim3(256), dim3(256), 0, stream, partials, partial2);
    hipLaunchKernelGGL(sda_pass2b, dim3(8),   dim3(256), 0, stream, partial2, inv);
    hipLaunchKernelGGL(sda_pass3,  dim3(2048), dim3(256), 0, stream, xc, out, inv);
}

// Round 16
// 46.385 us; speedup vs baseline: 5.2857x; 1.0525x over previous
//
#include <hip/hip_runtime.h>
#include <math.h>

// (b,n,h,d) = (4,8192,8,64), fp32.
// Groups: i=0: g=3,r=1,off=0,hmin=0,seg=2048  -> 8192 covered pos/b
//         i=1: g=3,r=2,off=1,hmin=3,seg=4096  -> 4096 covered pos/b (pos%2==1)
//         i=2: g=2,r=4,off=2,hmin=6,seg=8192  -> 2048 covered pos/b (pos%4==2)
//
// R16 = R15 with the nt-store compile fix (ext_vector_type, not HIP_vector_type).
//  (a) block-level LDS partial reduce in pass1 (R7-proven free): partials
//      5.5MB -> 1.4MB, pass2a work /4.
//  (b) nontemporal stores for final out (never re-read; preserves L2 for xc).
// 13 structural theories falsified across R1-R14; attention-shaped kernels
// pinned at ~2.4-3.6 TB/s combined. Only bytes+overhead move the total.

#define NB 4
#define NN 8192
#define NH 8
#define ND 64
#define NPART_STRIDE 192       // per-BLOCK partial: g*64 floats (max g=3)
#define N_BLOCKS_P1 1792       // 4b*(256+128+64) chunks of 32 positions

// compact-x element offsets (bf16 elements)
#define XBASE_G1 (32768u * 192u)               // after g0: 4b*8192 inst * 192
#define XBASE_G2 (XBASE_G1 + 16384u * 192u)    // after g1: 4b*4096 inst * 192

typedef float f32x4 __attribute__((ext_vector_type(4)));

__device__ __forceinline__ unsigned short f2b(float f) {   // rne bf16
    unsigned int u = __float_as_uint(f);
    u = (u + 0x7FFFu + ((u >> 16) & 1u)) >> 16;
    return (unsigned short)u;
}
__device__ __forceinline__ float b2f(unsigned short s) {
    return __uint_as_float(((unsigned int)s) << 16);
}

typedef float Red_t[3][64];    // per-wave slot: [q][d]

template<int G, int IT>
__device__ __forceinline__ void pass1_work(
    const float* __restrict__ Q, const float* __restrict__ K,
    const float* __restrict__ V, unsigned short* __restrict__ xc,
    float* __restrict__ partials, Red_t* red,
    int b, int chunk, int r, int off, int hmin, int seglen,
    size_t xbase, int ninst, int xrec)
{
    const int tid  = threadIdx.x;   // 256 threads = 4 waves
    const int w    = tid >> 6;
    const int lane = tid & 63;
    const int sg   = lane >> 4;     // 16-lane sub-group = one position
    const int l    = lane & 15;     // lane owns d in [4l, 4l+4)

    size_t rowbase[IT];
    int jj[IT];
    #pragma unroll
    for (int it = 0; it < IT; ++it) {
        const int j   = chunk * (16 * IT) + w * (4 * IT) + it * 4 + sg;
        const int pos = (j >> 11) * seglen + off + (j & 2047) * r;
        jj[it] = j;
        rowbase[it] = (((size_t)b * NN + pos) * NH + hmin) * ND + 4 * l;
    }

    float4 qv[IT][G], kv[IT][G], vv[IT][G];
    #pragma unroll
    for (int it = 0; it < IT; ++it)
        #pragma unroll
        for (int q = 0; q < G; ++q) {
            qv[it][q] = *(const float4*)(Q + rowbase[it] + q * ND);
            kv[it][q] = *(const float4*)(K + rowbase[it] + q * ND);
            vv[it][q] = *(const float4*)(V + rowbase[it] + q * ND);
        }

    float xs[G][4];
    #pragma unroll
    for (int q = 0; q < G; ++q)
        #pragma unroll
        for (int e = 0; e < 4; ++e) xs[q][e] = 0.f;

    #pragma unroll
    for (int it = 0; it < IT; ++it) {
        float sc[G][G];
        #pragma unroll
        for (int q = 0; q < G; ++q)
            #pragma unroll
            for (int k = 0; k < G; ++k)
                sc[q][k] = qv[it][q].x * kv[it][k].x + qv[it][q].y * kv[it][k].y
                         + qv[it][q].z * kv[it][k].z + qv[it][q].w * kv[it][k].w;

        // butterfly reduce across the 16 lanes of this sub-group
        #pragma unroll
        for (int o = 8; o >= 1; o >>= 1)
            #pragma unroll
            for (int q = 0; q < G; ++q)
                #pragma unroll
                for (int k = 0; k < G; ++k)
                    sc[q][k] += __shfl_xor(sc[q][k], o);

        #pragma unroll
        for (int q = 0; q < G; ++q) {
            float m = -INFINITY;
            #pragma unroll
            for (int k = 0; k < G; ++k) { sc[q][k] *= 0.125f; m = fmaxf(m, sc[q][k]); }
            float ssum = 0.f;
            #pragma unroll
            for (int k = 0; k < G; ++k) { sc[q][k] = __expf(sc[q][k] - m); ssum += sc[q][k]; }
            const float rs = 1.f / ssum;
            #pragma unroll
            for (int k = 0; k < G; ++k) sc[q][k] *= rs;
        }

        // compact bf16 record: [instance][q][64] elems, contiguous
        const size_t xo0 = xbase + ((size_t)b * ninst + jj[it]) * xrec;
        #pragma unroll
        for (int q = 0; q < G; ++q) {
            float xe0 = 0.f, xe1 = 0.f, xe2 = 0.f, xe3 = 0.f;
            #pragma unroll
            for (int k = 0; k < G; ++k) {
                const float aw = sc[q][k];
                xe0 += aw * vv[it][k].x; xe1 += aw * vv[it][k].y;
                xe2 += aw * vv[it][k].z; xe3 += aw * vv[it][k].w;
            }
            ushort4 u;
            u.x = f2b(xe0); u.y = f2b(xe1); u.z = f2b(xe2); u.w = f2b(xe3);
            *(ushort4*)(xc + xo0 + q * 64 + 4 * l) = u;
            xs[q][0] += xe0; xs[q][1] += xe1; xs[q][2] += xe2; xs[q][3] += xe3;
        }
    }

    // wave-level reduction across the 4 sub-groups (register-only)
    #pragma unroll
    for (int q = 0; q < G; ++q)
        #pragma unroll
        for (int e = 0; e < 4; ++e) {
            xs[q][e] += __shfl_xor(xs[q][e], 16);
            xs[q][e] += __shfl_xor(xs[q][e], 32);
        }

    // block-level reduction (R7-proven free): partials shrink 4x
    if (lane < 16)
        #pragma unroll
        for (int q = 0; q < G; ++q)
            *(float4*)&red[w][q][4 * l] =
                make_float4(xs[q][0], xs[q][1], xs[q][2], xs[q][3]);
    __syncthreads();

    if (tid < G * 64) {
        const int q = tid >> 6;
        const int d = tid & 63;
        partials[(size_t)blockIdx.x * NPART_STRIDE + q * 64 + d] =
            red[0][q][d] + red[1][q][d] + red[2][q][d] + red[3][q][d];
    }
}

__global__ __launch_bounds__(256)
void sda_pass1(const float* __restrict__ Q, const float* __restrict__ K,
               const float* __restrict__ V, unsigned short* __restrict__ xc,
               float* __restrict__ partials)
{
    __shared__ Red_t red[4];           // 3 KB
    const int bid = blockIdx.x;
    if (bid < 1024) {                      // group 0: 4 b * 256 chunks
        const int b = bid >> 8, chunk = bid & 255;
        pass1_work<3, 2>(Q, K, V, xc, partials, red, b, chunk, 1, 0, 0, 2048,
                         0, 8192, 192);
    } else if (bid < 1536) {               // group 1: 4 b * 128 chunks
        const int loc = bid - 1024;
        const int b = loc >> 7, chunk = loc & 127;
        pass1_work<3, 2>(Q, K, V, xc, partials, red, b, chunk, 2, 1, 3, 4096,
                         XBASE_G1, 4096, 192);
    } else {                               // group 2: 4 b * 64 chunks
        const int loc = bid - 1536;
        const int b = loc >> 6, chunk = loc & 63;
        pass1_work<2, 2>(Q, K, V, xc, partials, red, b, chunk, 4, 2, 6, 8192,
                         XBASE_G2, 2048, 128);
    }
}

// pass2a: 256 blocks = (bh 0..31) x (slice 0..7); coalesced block-partial reduce.
__global__ __launch_bounds__(256)
void sda_pass2a(const float* __restrict__ partials, float* __restrict__ partial2)
{
    const int bid   = blockIdx.x;
    const int bh    = bid >> 3;
    const int slice = bid & 7;
    const int b     = bh >> 3;
    const int h     = bh & 7;
    const int d     = threadIdx.x & 63;
    const int part  = threadIdx.x >> 6;   // 4-way split of the slice
    int qi, bstart, cnt;
    if (h < 3)      { qi = h;     bstart = b * 256;        cnt = 256; }
    else if (h < 6) { qi = h - 3; bstart = 1024 + b * 128; cnt = 128; }
    else            { qi = h - 6; bstart = 1536 + b * 64;  cnt = 64;  }
    const int len = cnt >> 3;             // 32 / 16 / 8
    const int c0  = bstart + slice * len;
    float s = 0.f;
    #pragma unroll 4
    for (int c = part; c < len; c += 4)
        s += partials[(size_t)(c0 + c) * NPART_STRIDE + qi * 64 + d];
    __shared__ float sred[4][64];
    sred[part][d] = s;
    __syncthreads();
    if (part == 0)
        partial2[(size_t)bid * 64 + d] = sred[0][d] + sred[1][d] + sred[2][d] + sred[3][d];
}

// pass2b: finish 8 slice-partials per (b,h,d) -> inv
__global__ __launch_bounds__(256)
void sda_pass2b(const float* __restrict__ partial2, float* __restrict__ inv)
{
    const int t = blockIdx.x * 256 + threadIdx.x;   // 2048 = bh*64 + d
    if (t >= NB * NH * ND) return;
    const int bh = t >> 6;
    const int d  = t & 63;
    float s = 0.f;
    #pragma unroll
    for (int sl = 0; sl < 8; ++sl)
        s += partial2[(size_t)(bh * 8 + sl) * 64 + d];
    inv[t] = 1.f / (3.f * (s + 1e-8f));
}

// pass3: read compact bf16 x (L2-friendly), scale, nt-store full out.
__global__ __launch_bounds__(256)
void sda_pass3(const unsigned short* __restrict__ xc, float* __restrict__ out,
               const float* __restrict__ inv)
{
    const int total4 = NB * NN * NH * ND / 4;   // 4,194,304 float4s
    for (int idx = blockIdx.x * 256 + threadIdx.x; idx < total4;
         idx += gridDim.x * 256) {
        const int d4  = idx & 15;
        const int rem = idx >> 4;
        const int h   = rem & 7;
        const int pos = (rem >> 3) & 8191;
        const int b   = rem >> 16;

        f32x4 o = {0.f, 0.f, 0.f, 0.f};
        size_t xo = (size_t)-1;
        if (h < 3) {
            xo = ((size_t)b * 8192 + pos) * 192 + h * 64 + 4 * d4;
        } else if (h < 6) {
            if (pos & 1) {
                const int j = (pos >> 12) * 2048 + ((pos & 4095) >> 1);
                xo = XBASE_G1 + ((size_t)b * 4096 + j) * 192 + (h - 3) * 64 + 4 * d4;
            }
        } else {
            if ((pos & 3) == 2) {
                const int j = (pos - 2) >> 2;
                xo = XBASE_G2 + ((size_t)b * 2048 + j) * 128 + (h - 6) * 64 + 4 * d4;
            }
        }
        if (xo != (size_t)-1) {
            const ushort4 u = *(const ushort4*)(xc + xo);
            const float4 f = ((const float4*)inv)[(b * 8 + h) * 16 + d4];
            o = (f32x4){ b2f(u.x) * f.x, b2f(u.y) * f.y,
                         b2f(u.z) * f.z, b2f(u.w) * f.w };
        }
        __builtin_nontemporal_store(o, (f32x4*)out + idx);
    }
}

extern "C" void kernel_launch(void* const* d_in, const int* in_sizes, int n_in,
                              void* d_out, int out_size, void* d_ws, size_t ws_size,
                              hipStream_t stream)
{
    const float* Q = (const float*)d_in[0];
    const float* K = (const float*)d_in[1];
    const float* V = (const float*)d_in[2];
    float* out = (float*)d_out;

    unsigned short* xc = (unsigned short*)d_ws;                    // ~21 MB bf16
    float* partials = (float*)((char*)d_ws + 22u * 1024u * 1024u); // 1.4 MB
    float* partial2 = partials + (size_t)N_BLOCKS_P1 * NPART_STRIDE;
    float* inv      = partial2 + 256 * 64;

    hipLaunchKernelGGL(sda_pass1,  dim3(N_BLOCKS_P1), dim3(256), 0, stream,
                       Q, K, V, xc, partials);
    hipLaunchKernelGGL(sda_pass2a, dim3(256), dim3(256), 0, stream, partials, partial2);
    hipLaunchKernelGGL(sda_pass2b, dim3(8),   dim3(256), 0, stream, partial2, inv);
    hipLaunchKernelGGL(sda_pass3,  dim3(2048), dim3(256), 0, stream, xc, out, inv);
}